// Round 1
// baseline (228.846 us; speedup 1.0000x reference)
//
#include <hip/hip_runtime.h>
#include <hip/hip_fp16.h>

typedef _Float16 half4_t __attribute__((ext_vector_type(4)));
typedef _Float16 half8_t __attribute__((ext_vector_type(8)));
typedef float   float4_t __attribute__((ext_vector_type(4)));

namespace {
constexpr int kB      = 16;    // batch
constexpr int kL      = 4096;  // Lq == Lk
constexpr int kD      = 64;    // head dim
constexpr int kQTile  = 128;   // q rows per block
constexpr int kWQ     = 32;    // q rows per wave
constexpr int kBK     = 64;    // keys per iteration
constexpr int kStride = 72;    // padded LDS row stride (halves): +8 to break bank cycles
}

// Flash attention forward.
// S^T = K*Q^T via mfma_f32_16x16x32_f16: C layout col=lane&15 (qrow), row=4*quad+reg (key).
// That C layout IS the A layout of mfma_f32_16x16x16f16 (m=lane&15, k=4*quad+i),
// so P = exp2(S - m) feeds PV entirely in-register (no LDS round-trip for P).
__global__ __launch_bounds__(256, 3)
void fa_fwd(const float* __restrict__ Q, const float* __restrict__ K,
            const float* __restrict__ V, const float* __restrict__ scale_ptr,
            float* __restrict__ Out)
{
    __shared__ __align__(16) _Float16 Ksh[kBK * kStride];   // Ksh[key][d]
    __shared__ __align__(16) _Float16 Vsh[kD * kStride];    // Vsh[d][key]  (transposed)

    const int tid  = threadIdx.x;
    const int wave = tid >> 6;
    const int lane = tid & 63;
    const int c    = lane & 15;   // intra-16 index
    const int qd   = lane >> 4;   // quad 0..3

    const int b  = blockIdx.y;
    const int q0 = blockIdx.x * kQTile + wave * kWQ;

    // fold 1/scale and log2(e) into Q so softmax uses raw exp2
    const float qscale = 1.4426950408889634f / scale_ptr[0];

    const float* Qb = Q + (size_t)b * kL * kD;
    const float* Kb = K + (size_t)b * kL * kD;
    const float* Vb = V + (size_t)b * kL * kD;

    // ---- Q fragments (B-operand of 16x16x32: n=lane&15=qrow, k=8*quad+j=d) ----
    half8_t qfrag[2][2];
#pragma unroll
    for (int qt = 0; qt < 2; ++qt) {
        const float* qrow = Qb + (size_t)(q0 + qt * 16 + c) * kD;
#pragma unroll
        for (int dk = 0; dk < 2; ++dk) {
            const float* p = qrow + dk * 32 + qd * 8;
            half8_t h;
#pragma unroll
            for (int j = 0; j < 8; ++j) h[j] = (_Float16)(p[j] * qscale);
            qfrag[qt][dk] = h;
        }
    }

    float4_t O[2][4];
#pragma unroll
    for (int qt = 0; qt < 2; ++qt)
#pragma unroll
        for (int dt = 0; dt < 4; ++dt) O[qt][dt] = (float4_t)0.0f;

    float m_run[2] = {-__builtin_inff(), -__builtin_inff()};
    float l_run[2] = {0.0f, 0.0f};

    for (int kb = 0; kb < kL; kb += kBK) {
        __syncthreads();  // protect LDS from previous iteration's readers

        // ---- stage K tile (row-major, fp32 -> fp16), coalesced 256B rows ----
#pragma unroll
        for (int i = 0; i < 4; ++i) {
            const int task = tid + 256 * i;
            const int c4   = task & 15;
            const int row  = task >> 4;
            const float4 f = *(const float4*)(Kb + (size_t)(kb + row) * kD + c4 * 4);
            half4_t h;
            h[0] = (_Float16)f.x; h[1] = (_Float16)f.y;
            h[2] = (_Float16)f.z; h[3] = (_Float16)f.w;
            *(half4_t*)(&Ksh[row * kStride + c4 * 4]) = h;
        }
        // ---- stage V tile transposed (Vsh[d][key]); L1 absorbs the strided reads ----
#pragma unroll
        for (int i = 0; i < 4; ++i) {
            const int task = tid + 256 * i;
            const int row  = task & 63;
            const int c4   = task >> 6;
            const float4 f = *(const float4*)(Vb + (size_t)(kb + row) * kD + c4 * 4);
            Vsh[(c4 * 4 + 0) * kStride + row] = (_Float16)f.x;
            Vsh[(c4 * 4 + 1) * kStride + row] = (_Float16)f.y;
            Vsh[(c4 * 4 + 2) * kStride + row] = (_Float16)f.z;
            Vsh[(c4 * 4 + 3) * kStride + row] = (_Float16)f.w;
        }
        __syncthreads();

        // ---- K fragments (A-operand: m=lane&15=key, k=8*quad+j=d) ----
        half8_t kf[4][2];
#pragma unroll
        for (int kt = 0; kt < 4; ++kt)
#pragma unroll
            for (int dk = 0; dk < 2; ++dk)
                kf[kt][dk] = *(const half8_t*)(&Ksh[(kt * 16 + c) * kStride + dk * 32 + qd * 8]);

        // ---- S^T = K * Q^T ----
        float4_t S[4][2];
#pragma unroll
        for (int kt = 0; kt < 4; ++kt)
#pragma unroll
            for (int qt = 0; qt < 2; ++qt) {
                float4_t acc = (float4_t)0.0f;
                acc = __builtin_amdgcn_mfma_f32_16x16x32_f16(kf[kt][0], qfrag[qt][0], acc, 0, 0, 0);
                acc = __builtin_amdgcn_mfma_f32_16x16x32_f16(kf[kt][1], qfrag[qt][1], acc, 0, 0, 0);
                S[kt][qt] = acc;
            }

        // ---- online softmax in S^T layout (column = q-row) ----
        float alpha[2];
#pragma unroll
        for (int qt = 0; qt < 2; ++qt) {
            float tm = S[0][qt][0];
#pragma unroll
            for (int kt = 0; kt < 4; ++kt)
#pragma unroll
                for (int r = 0; r < 4; ++r) tm = fmaxf(tm, S[kt][qt][r]);
            tm = fmaxf(tm, __shfl_xor(tm, 16));
            tm = fmaxf(tm, __shfl_xor(tm, 32));
            const float mn = fmaxf(m_run[qt], tm);
            alpha[qt] = __builtin_amdgcn_exp2f(m_run[qt] - mn);  // first iter: exp2(-inf)=0
            m_run[qt] = mn;
            float rs = 0.0f;
#pragma unroll
            for (int kt = 0; kt < 4; ++kt)
#pragma unroll
                for (int r = 0; r < 4; ++r) {
                    const float pv = __builtin_amdgcn_exp2f(S[kt][qt][r] - mn);
                    S[kt][qt][r] = pv;
                    rs += pv;
                }
            rs += __shfl_xor(rs, 16);
            rs += __shfl_xor(rs, 32);
            l_run[qt] = l_run[qt] * alpha[qt] + rs;
        }

        // ---- rescale O (broadcast alpha from q-row=lane&15 layout to O rows 4*qd+r) ----
#pragma unroll
        for (int qt = 0; qt < 2; ++qt)
#pragma unroll
            for (int r = 0; r < 4; ++r) {
                const float a = __shfl(alpha[qt], qd * 4 + r);
#pragma unroll
                for (int dt = 0; dt < 4; ++dt) O[qt][dt][r] *= a;
            }

        // ---- P fragments: in-register cvt, already in 16x16x16 A layout ----
        half4_t pf[4][2];
#pragma unroll
        for (int kt = 0; kt < 4; ++kt)
#pragma unroll
            for (int qt = 0; qt < 2; ++qt) {
                half4_t h;
                h[0] = (_Float16)S[kt][qt][0]; h[1] = (_Float16)S[kt][qt][1];
                h[2] = (_Float16)S[kt][qt][2]; h[3] = (_Float16)S[kt][qt][3];
                pf[kt][qt] = h;
            }

        // ---- O += P * V  (B-operand: n=lane&15=d, k=4*quad+i=key -> contiguous in Vsh) ----
#pragma unroll
        for (int kt = 0; kt < 4; ++kt)
#pragma unroll
            for (int dt = 0; dt < 4; ++dt) {
                const half4_t vf = *(const half4_t*)(&Vsh[(dt * 16 + c) * kStride + kt * 16 + qd * 4]);
#pragma unroll
                for (int qt = 0; qt < 2; ++qt)
                    O[qt][dt] = __builtin_amdgcn_mfma_f32_16x16x16f16(pf[kt][qt], vf, O[qt][dt], 0, 0, 0);
            }
    }

    // ---- epilogue: normalize by l and store ----
#pragma unroll
    for (int qt = 0; qt < 2; ++qt)
#pragma unroll
        for (int r = 0; r < 4; ++r) {
            const float lr  = __shfl(l_run[qt], qd * 4 + r);
            const float inv = 1.0f / lr;
            const int qrow  = q0 + qt * 16 + qd * 4 + r;
            float* op = Out + ((size_t)b * kL + qrow) * kD;
#pragma unroll
            for (int dt = 0; dt < 4; ++dt)
                op[dt * 16 + c] = O[qt][dt][r] * inv;
        }
}

extern "C" void kernel_launch(void* const* d_in, const int* in_sizes, int n_in,
                              void* d_out, int out_size, void* d_ws, size_t ws_size,
                              hipStream_t stream) {
    const float* Q = (const float*)d_in[0];
    const float* K = (const float*)d_in[1];
    const float* V = (const float*)d_in[2];
    const float* s = (const float*)d_in[3];
    float* out = (float*)d_out;
    dim3 grid(kL / kQTile, kB, 1);
    dim3 block(256, 1, 1);
    fa_fwd<<<grid, block, 0, stream>>>(Q, K, V, s, out);
}